// Round 2
// baseline (88.621 us; speedup 1.0000x reference)
//
#include <hip/hip_runtime.h>
#include <hip/hip_bf16.h>

#define HIDDEN 64
#define NLAYERS 4
#define NZ 120
#define DIM_H 256
#define DIM_G 65536

// ws layout (bytes):
//   [0..4)      uint oddZeroCount   (int64-detection)
//   [4..484)    uint counts[120]
//   [512..1024) double gfeat[64]
//   [4096..266240) float graw[65536]
#define WS_FLAG_OFF   0
#define WS_CNT_OFF    4
#define WS_GF_OFF     512
#define WS_GRAW_OFF   4096

// ---------------- K1: detect int64-materialized Z ----------------
__global__ void k_detect(const int* __restrict__ Z, int n, unsigned* __restrict__ flag) {
    unsigned local = 0;
    int stride = gridDim.x * blockDim.x;
    for (int i = blockIdx.x * blockDim.x + threadIdx.x; i < n; i += stride)
        if ((i & 1) && Z[i] == 0) local++;
    // wave-64 reduce
    #pragma unroll
    for (int off = 32; off > 0; off >>= 1)
        local += __shfl_down(local, off, 64);
    if ((threadIdx.x & 63) == 0 && local) atomicAdd(flag, local);
}

// ---------------- K2: histogram of Z ----------------
__global__ void k_hist(const int* __restrict__ Z, int n,
                       const unsigned* __restrict__ flag, unsigned* __restrict__ counts) {
    // if Z is int64 little-endian with values in [0,120), every odd int32 is 0.
    bool is64 = (*flag > (unsigned)(n / 4));
    __shared__ unsigned h[NZ];
    for (int b = threadIdx.x; b < NZ; b += blockDim.x) h[b] = 0;
    __syncthreads();
    int stride = gridDim.x * blockDim.x;
    for (int i = blockIdx.x * blockDim.x + threadIdx.x; i < n; i += stride) {
        int v = is64 ? Z[2 * i] : Z[i];
        v = min(max(v, 0), NZ - 1);
        atomicAdd(&h[v], 1u);
    }
    __syncthreads();
    for (int b = threadIdx.x; b < NZ; b += blockDim.x)
        if (h[b]) atomicAdd(&counts[b], h[b]);
}

// ---------------- K3: 120 tiny MLPs, weighted-sum into gfeat (fp64) ----------------
__global__ void k_mlp(const float* __restrict__ embed, const float* __restrict__ Wtp,
                      const unsigned* __restrict__ counts, double* __restrict__ gfeat) {
    int z = blockIdx.x;           // 0..119
    int c = threadIdx.x;          // 0..63
    __shared__ float xs[HIDDEN];
    float x = embed[z * HIDDEN + c];
    for (int l = 0; l < NLAYERS; ++l) {
        xs[c] = x;
        __syncthreads();
        float u = 0.f;
        const float* W = Wtp + l * HIDDEN * HIDDEN;
        #pragma unroll
        for (int k = 0; k < HIDDEN; ++k) u += xs[k] * W[k * HIDDEN + c];
        u *= 0.125f;                       // * y0 * INV_SQRT_H
        x = u / (1.f + expf(-u));          // silu
        __syncthreads();
    }
    atomicAdd(&gfeat[c], (double)x * (double)counts[z]);
}

// ---------------- K4: raw g = gfeat @ w_g + b_g  ----------------
__global__ void k_graw(const double* __restrict__ gfeat, const float* __restrict__ w_g,
                       const float* __restrict__ b_g, float* __restrict__ graw) {
    __shared__ float gf[HIDDEN];
    if (threadIdx.x < HIDDEN) gf[threadIdx.x] = (float)gfeat[threadIdx.x];
    __syncthreads();
    int p = blockIdx.x * blockDim.x + threadIdx.x;   // 0..65535
    float acc = b_g[p];
    #pragma unroll
    for (int c = 0; c < HIDDEN; ++c) acc += gf[c] * w_g[c * DIM_G + p];
    graw[p] = acc;
}

// ---------------- K5: symmetrize h and g, write float32 output ----------------
__global__ void k_sym(const double* __restrict__ gfeat, const float* __restrict__ w_h,
                      const float* __restrict__ b_h, const float* __restrict__ graw,
                      float* __restrict__ out) {
    if (blockIdx.x == 0) {
        __shared__ float gf[HIDDEN];
        if (threadIdx.x < HIDDEN) gf[threadIdx.x] = (float)gfeat[threadIdx.x];
        __syncthreads();
        int p = threadIdx.x;                 // 0..255
        int i = p >> 4, j = p & 15;
        int pt = j * 16 + i;
        float a = b_h[p], b = b_h[pt];
        #pragma unroll
        for (int c = 0; c < HIDDEN; ++c) {
            a += gf[c] * w_h[c * DIM_H + p];
            b += gf[c] * w_h[c * DIM_H + pt];
        }
        out[p] = 0.5f * (a + b);
    } else {
        int q = (int)(blockIdx.x - 1) * (int)blockDim.x + (int)threadIdx.x;  // 0..65535
        int l = q & 15, k = (q >> 4) & 15, j = (q >> 8) & 15, i = (q >> 12) & 15;
        #define IDX4(a,b,c,d) ((((a)*16+(b))*16+(c))*16+(d))
        float s = graw[IDX4(i,j,k,l)] + graw[IDX4(j,i,k,l)]
                + graw[IDX4(i,j,l,k)] + graw[IDX4(j,i,l,k)]
                + graw[IDX4(k,l,i,j)] + graw[IDX4(l,k,i,j)]
                + graw[IDX4(k,l,j,i)] + graw[IDX4(l,k,j,i)];
        out[DIM_H + q] = s * 0.125f;
    }
}

extern "C" void kernel_launch(void* const* d_in, const int* in_sizes, int n_in,
                              void* d_out, int out_size, void* d_ws, size_t ws_size,
                              hipStream_t stream) {
    const int*   Z     = (const int*)  d_in[0];
    // d_in[1] = pos (unused), d_in[2] = ghost (unused)
    const float* embed = (const float*)d_in[3];
    const float* Wtp   = (const float*)d_in[4];
    const float* w_h   = (const float*)d_in[5];
    const float* b_h   = (const float*)d_in[6];
    const float* w_g   = (const float*)d_in[7];
    const float* b_g   = (const float*)d_in[8];
    float* out = (float*)d_out;

    int n = in_sizes[0];                        // 1,000,000 nodes

    char* ws = (char*)d_ws;
    unsigned* flag   = (unsigned*)(ws + WS_FLAG_OFF);
    unsigned* counts = (unsigned*)(ws + WS_CNT_OFF);
    double*   gfeat  = (double*)  (ws + WS_GF_OFF);
    float*    graw   = (float*)   (ws + WS_GRAW_OFF);

    // zero flag + counts + gfeat accumulators
    hipMemsetAsync(d_ws, 0, 1024, stream);

    k_detect<<<1024, 256, 0, stream>>>(Z, n, flag);
    k_hist  <<<1024, 256, 0, stream>>>(Z, n, flag, counts);
    k_mlp   <<<NZ, HIDDEN, 0, stream>>>(embed, Wtp, counts, gfeat);
    k_graw  <<<DIM_G / 256, 256, 0, stream>>>(gfeat, w_g, b_g, graw);
    k_sym   <<<1 + DIM_G / 256, 256, 0, stream>>>(gfeat, w_h, b_h, graw, out);
}